// Round 13
// baseline (435.981 us; speedup 1.0000x reference)
//
#include <hip/hip_runtime.h>

typedef __attribute__((ext_vector_type(8))) short bf16x8;   // MFMA A/B frag
typedef __attribute__((ext_vector_type(4))) float f32x4;    // MFMA C/D frag
typedef __attribute__((ext_vector_type(4))) short s16x4;    // 4 bf16 (8 B)

__device__ __forceinline__ unsigned cvt_pk(float lo, float hi) {
  unsigned r;
  asm("v_cvt_pk_bf16_f32 %0, %1, %2" : "=v"(r) : "v"(lo), "v"(hi));
  return r;
}
__device__ __forceinline__ float bf2f(short s) {
  return __uint_as_float(((unsigned)(unsigned short)s) << 16);
}

#define LOG2E  1.4426950408889634f
#define LOG2E2 2.8853900817779268f

// ---------- geometry ----------
// ws per component: 4 matrices as A-operand fragments (W^T strips), bf16,
// PRESCALED: W1a,W1b by -log2e, W2 by +log2e, W3 by -log2e.
#define WS_MAT 32768
#define WS_COMP 131072
#define NODE_BLOCKS 3125
#define EDGE_BLOCKS 6250
#define GLOB_BLOCKS 32
#define NBLOCKS (NODE_BLOCKS + EDGE_BLOCKS + GLOB_BLOCKS)   // 9407

// swizzled byte offset within a [16 rows][256 B] LDS tile
#define SWZ(row, byte) ((row) * 256 + ((byte) ^ (((row) & 7) << 4)))

__global__ __launch_bounds__(256) void prep_weights(
    const float* __restrict__ W1, const float* __restrict__ W2,
    const float* __restrict__ W3, unsigned char* __restrict__ wsc) {
  const int m = blockIdx.x;   // 0=W1a 1=W1b 2=W2 3=W3
  const float* src; int rowoff = 0; float sc;
  if (m == 0)      { src = W1; sc = -LOG2E; }
  else if (m == 1) { src = W1; rowoff = 128; sc = -LOG2E; }
  else if (m == 2) { src = W2; sc =  LOG2E; }
  else             { src = W3; sc = -LOG2E; }
  short* dst = (short*)(wsc + (size_t)m * WS_MAT);
  for (int fi = threadIdx.x; fi < 2048; fi += 256) {
    int w = fi >> 8, kc = (fi >> 6) & 3, lane = fi & 63;
    int cc = lane & 15, gg = lane >> 4;
    int wcol = 16 * w + cc;
    int kb = 32 * kc + 8 * gg + rowoff;
    union { bf16x8 h; unsigned u[4]; } v;
#pragma unroll
    for (int j = 0; j < 4; ++j)
      v.u[j] = cvt_pk(sc * src[(size_t)(kb + 2 * j) * 128 + wcol],
                      sc * src[(size_t)(kb + 2 * j + 1) * 128 + wcol]);
    *(bf16x8*)(dst + (size_t)fi * 8) = v.h;
  }
}

__global__ __launch_bounds__(512, 4) void glstm(
    const float* __restrict__ xs, const float* __restrict__ es,
    const float* __restrict__ gs, const unsigned char* __restrict__ ws,
    const float* __restrict__ b1n, const float* __restrict__ b2n, const float* __restrict__ b3n,
    const float* __restrict__ b1e, const float* __restrict__ b2e, const float* __restrict__ b3e,
    const float* __restrict__ b1g, const float* __restrict__ b2g, const float* __restrict__ b3g,
    float* __restrict__ dout) {
  // DISTINCT shared objects: compiler-provable no-alias between x reads
  // and out writes -> pre-phase reads/MFMAs can overlap ser-phase chain.
  __shared__ __align__(16) short xbuf[3][2048];   // x(t) bf16 tiles, 4 KB each
  __shared__ __align__(16) short obuf[2][2048];   // out(t) bf16 tiles
  __shared__ float blds[384];                     // prescaled biases

  const int bid = blockIdx.x, tid = threadIdx.x;
  const float* X; const float *B1, *B2, *B3; float *S, *O; int M, unit, comp;
  if (bid < NODE_BLOCKS) {
    X = xs; M = 50000;  S = dout;              O = dout + 19265536L;
    unit = bid; comp = 0; B1 = b1n; B2 = b2n; B3 = b3n;
  } else if (bid < NODE_BLOCKS + EDGE_BLOCKS) {
    X = es; M = 100000; S = dout + 6400000L;   O = dout + 25665536L;
    unit = bid - NODE_BLOCKS; comp = 1; B1 = b1e; B2 = b2e; B3 = b3e;
  } else {
    X = gs; M = 512;    S = dout + 19200000L;  O = dout + 38465536L;
    unit = bid - (NODE_BLOCKS + EDGE_BLOCKS); comp = 2; B1 = b1g; B2 = b2g; B3 = b3g;
  }

  const int w = tid >> 6, l = tid & 63, c = l & 15, g = l >> 4;
  const int Ra = unit * 16;

  // weights -> registers (once; reused across all rows and steps)
  bf16x8 wA[4][4];
  {
    const short* wsrc = (const short*)(ws + (size_t)comp * WS_COMP);
#pragma unroll
    for (int m = 0; m < 4; ++m)
#pragma unroll
      for (int kc = 0; kc < 4; ++kc)
        wA[m][kc] = *(const bf16x8*)(wsrc + (size_t)m * 16384 + ((w * 4 + kc) * 64 + l) * 8);
  }

  // biases -> LDS, prescaled to match the weight prescale
  if (tid < 128) {
    blds[tid]       = -LOG2E * B1[tid];
    blds[128 + tid] =  LOG2E * B2[tid];
    blds[256 + tid] = -LOG2E * B3[tid];
  }

  const int srow = tid >> 5;              // 0..15
  const int sbyte = (tid & 31) * 8;       // bf16 byte col (8 B per thread)
  const int scol = (tid & 31) * 4;        // f32 col
  const int bo = 16 * w + 4 * g;

  // ---- prologue: stage x(0)->xbuf[0], x(1)->xbuf[1]
  {
    const float* p0 = X + (size_t)(Ra + srow) * 128 + scol;
    const float* p1 = p0 + (size_t)M * 128;
    f32x4 a0 = *(const f32x4*)p0;
    f32x4 a1 = *(const f32x4*)p1;
    union { s16x4 v; unsigned u[2]; } o;
    o.u[0] = cvt_pk(a0[0], a0[1]); o.u[1] = cvt_pk(a0[2], a0[3]);
    *(s16x4*)((char*)xbuf[0] + SWZ(srow, sbyte)) = o.v;
    o.u[0] = cvt_pk(a1[0], a1[1]); o.u[1] = cvt_pk(a1[2], a1[3]);
    *(s16x4*)((char*)xbuf[1] + SWZ(srow, sbyte)) = o.v;
  }
  __syncthreads();

  // state init = x[0] (bf16-rounded); step-0 x-terms from xbuf[0]
  f32x4 st, uu, g3, ax;
  {
    s16x4 e = *(const s16x4*)((char*)xbuf[0] + SWZ(c, 32 * w + 8 * g));
#pragma unroll
    for (int ri = 0; ri < 4; ++ri) st[ri] = bf2f(e[ri]);

    bf16x8 xf[4];
#pragma unroll
    for (int kc = 0; kc < 4; ++kc)
      xf[kc] = *(const bf16x8*)((char*)xbuf[0] + SWZ(c, 64 * kc + 16 * g));
    s16x4 xe4 = *(const s16x4*)((char*)xbuf[0] + SWZ(c, 32 * w + 8 * g));
    f32x4 aX = *(const f32x4*)(blds + bo);
    f32x4 aB = *(const f32x4*)(blds + 128 + bo);
    f32x4 aC = *(const f32x4*)(blds + 256 + bo);
#pragma unroll
    for (int kc = 0; kc < 4; ++kc) {
      aX = __builtin_amdgcn_mfma_f32_16x16x32_bf16(wA[1][kc], xf[kc], aX, 0, 0, 0);
      aB = __builtin_amdgcn_mfma_f32_16x16x32_bf16(wA[2][kc], xf[kc], aB, 0, 0, 0);
      aC = __builtin_amdgcn_mfma_f32_16x16x32_bf16(wA[3][kc], xf[kc], aC, 0, 0, 0);
    }
#pragma unroll
    for (int p = 0; p < 2; ++p) {
      const int r0 = 2 * p, r1 = 2 * p + 1;
      float A0 = __builtin_amdgcn_exp2f(aB[r0]);
      float A1 = __builtin_amdgcn_exp2f(aB[r1]);
      float E0 = __builtin_amdgcn_exp2f(LOG2E2 * bf2f(xe4[r0]));
      float E1 = __builtin_amdgcn_exp2f(LOG2E2 * bf2f(xe4[r1]));
      float du0 = (1.f + A0) * (E0 + 1.f);
      float du1 = (1.f + A1) * (E1 + 1.f);
      float ru = __builtin_amdgcn_rcpf(du0 * du1);
      uu[r0] = (A0 * (E0 - 1.f)) * (ru * du1);
      uu[r1] = (A1 * (E1 - 1.f)) * (ru * du0);
      float C0 = __builtin_amdgcn_exp2f(aC[r0]);
      float C1 = __builtin_amdgcn_exp2f(aC[r1]);
      float dg0 = 1.f + C0, dg1 = 1.f + C1;
      float rg = __builtin_amdgcn_rcpf(dg0 * dg1);
      g3[r0] = rg * dg1;
      g3[r1] = rg * dg0;
    }
    ax = aX;
  }

#pragma unroll 1
  for (int t = 0; t < 8; ++t) {
    const int xri = (t + 1) % 3;        // x(t+1) buffer (pre reads)
    const int xwi = (t + 2) % 3;        // x(t+2) buffer (stage write)
    const char* ofs = (t == 0) ? (const char*)xbuf[0] : (const char*)obuf[(t + 1) & 1];
    char* owf = (char*)obuf[t & 1];
    const char* xrp = (const char*)xbuf[xri];

    // A. issue x(t+2) global prefetch
    f32x4 pa;
    const bool pf = (t < 6);
    if (pf) {
      const float* p = X + ((size_t)(t + 2) * M + Ra + srow) * 128 + scol;
      pa = *(const f32x4*)p;
    }

    // B. issue of-read FIRST (longest cross-wave dependency)
    bf16x8 of[4];
#pragma unroll
    for (int kc = 0; kc < 4; ++kc)
      of[kc] = *(const bf16x8*)(ofs + SWZ(c, 64 * kc + 16 * g));

    // C+D. pre reads + 12 independent MFMAs (fill the of-wait)
    f32x4 aXn, aBn, aCn; s16x4 xe4;
    if (t < 7) {
      bf16x8 xf[4];
#pragma unroll
      for (int kc = 0; kc < 4; ++kc)
        xf[kc] = *(const bf16x8*)(xrp + SWZ(c, 64 * kc + 16 * g));
      xe4 = *(const s16x4*)(xrp + SWZ(c, 32 * w + 8 * g));
      aXn = *(const f32x4*)(blds + bo);
      aBn = *(const f32x4*)(blds + 128 + bo);
      aCn = *(const f32x4*)(blds + 256 + bo);
#pragma unroll
      for (int kc = 0; kc < 4; ++kc) {
        aXn = __builtin_amdgcn_mfma_f32_16x16x32_bf16(wA[1][kc], xf[kc], aXn, 0, 0, 0);
        aBn = __builtin_amdgcn_mfma_f32_16x16x32_bf16(wA[2][kc], xf[kc], aBn, 0, 0, 0);
        aCn = __builtin_amdgcn_mfma_f32_16x16x32_bf16(wA[3][kc], xf[kc], aCn, 0, 0, 0);
      }
    }

    // E. ser MFMAs
    f32x4 aA = ax;
#pragma unroll
    for (int kc = 0; kc < 4; ++kc)
      aA = __builtin_amdgcn_mfma_f32_16x16x32_bf16(wA[0][kc], of[kc], aA, 0, 0, 0);

    // F. ser trans: st update (uses current uu,g3), out write
    {
      float N0 = __builtin_amdgcn_exp2f(aA[0]);
      float N1 = __builtin_amdgcn_exp2f(aA[1]);
      float N2 = __builtin_amdgcn_exp2f(aA[2]);
      float N3 = __builtin_amdgcn_exp2f(aA[3]);
      float d0 = 1.f + N0, d1 = 1.f + N1, d2 = 1.f + N2, d3 = 1.f + N3;
      float rf01 = __builtin_amdgcn_rcpf(d0 * d1);
      float rf23 = __builtin_amdgcn_rcpf(d2 * d3);
      st[0] = st[0] * (rf01 * d1) + uu[0];
      st[1] = st[1] * (rf01 * d0) + uu[1];
      st[2] = st[2] * (rf23 * d3) + uu[2];
      st[3] = st[3] * (rf23 * d2) + uu[3];
      if (t < 7) {
        float E0 = __builtin_amdgcn_exp2f(LOG2E2 * st[0]);
        float E1 = __builtin_amdgcn_exp2f(LOG2E2 * st[1]);
        float E2 = __builtin_amdgcn_exp2f(LOG2E2 * st[2]);
        float E3 = __builtin_amdgcn_exp2f(LOG2E2 * st[3]);
        float t0 = 1.f + E0, t1 = 1.f + E1, t2 = 1.f + E2, t3 = 1.f + E3;
        float rt01 = __builtin_amdgcn_rcpf(t0 * t1);
        float rt23 = __builtin_amdgcn_rcpf(t2 * t3);
        f32x4 ov;
        ov[0] = (1.f - 2.f * (rt01 * t1)) * g3[0];
        ov[1] = (1.f - 2.f * (rt01 * t0)) * g3[1];
        ov[2] = (1.f - 2.f * (rt23 * t3)) * g3[2];
        ov[3] = (1.f - 2.f * (rt23 * t2)) * g3[3];
        union { s16x4 v; unsigned uu2[2]; } ob;
        ob.uu2[0] = cvt_pk(ov[0], ov[1]);
        ob.uu2[1] = cvt_pk(ov[2], ov[3]);
        *(s16x4*)(owf + SWZ(c, 32 * w + 8 * g)) = ob.v;
      }
    }

    // G. pre trans: next-step uu, g3, ax
    if (t < 7) {
#pragma unroll
      for (int p = 0; p < 2; ++p) {
        const int r0 = 2 * p, r1 = 2 * p + 1;
        float A0 = __builtin_amdgcn_exp2f(aBn[r0]);
        float A1 = __builtin_amdgcn_exp2f(aBn[r1]);
        float E0 = __builtin_amdgcn_exp2f(LOG2E2 * bf2f(xe4[r0]));
        float E1 = __builtin_amdgcn_exp2f(LOG2E2 * bf2f(xe4[r1]));
        float du0 = (1.f + A0) * (E0 + 1.f);
        float du1 = (1.f + A1) * (E1 + 1.f);
        float ru = __builtin_amdgcn_rcpf(du0 * du1);
        uu[r0] = (A0 * (E0 - 1.f)) * (ru * du1);
        uu[r1] = (A1 * (E1 - 1.f)) * (ru * du0);
        float C0 = __builtin_amdgcn_exp2f(aCn[r0]);
        float C1 = __builtin_amdgcn_exp2f(aCn[r1]);
        float dg0 = 1.f + C0, dg1 = 1.f + C1;
        float rg = __builtin_amdgcn_rcpf(dg0 * dg1);
        g3[r0] = rg * dg1;
        g3[r1] = rg * dg0;
      }
      ax = aXn;
    }

    // H. write staged x(t+2)
    if (pf) {
      union { s16x4 v; unsigned u[2]; } o;
      o.u[0] = cvt_pk(pa[0], pa[1]); o.u[1] = cvt_pk(pa[2], pa[3]);
      *(s16x4*)((char*)xbuf[xwi] + SWZ(srow, sbyte)) = o.v;
    }
    if (t < 7) __syncthreads();
  }

  // ---- epilogue: out = tanh(st)*g3 (g3 holds step-7 values), store f32
  {
    float E0 = __builtin_amdgcn_exp2f(LOG2E2 * st[0]);
    float E1 = __builtin_amdgcn_exp2f(LOG2E2 * st[1]);
    float E2 = __builtin_amdgcn_exp2f(LOG2E2 * st[2]);
    float E3 = __builtin_amdgcn_exp2f(LOG2E2 * st[3]);
    float t0 = 1.f + E0, t1 = 1.f + E1, t2 = 1.f + E2, t3 = 1.f + E3;
    float rt01 = __builtin_amdgcn_rcpf(t0 * t1);
    float rt23 = __builtin_amdgcn_rcpf(t2 * t3);
    f32x4 ov;
    ov[0] = (1.f - 2.f * (rt01 * t1)) * g3[0];
    ov[1] = (1.f - 2.f * (rt01 * t0)) * g3[1];
    ov[2] = (1.f - 2.f * (rt23 * t3)) * g3[2];
    ov[3] = (1.f - 2.f * (rt23 * t2)) * g3[3];
    size_t o = (size_t)(Ra + c) * 128 + 16 * w + 4 * g;
    *(f32x4*)(S + o) = st;
    *(f32x4*)(O + o) = ov;
  }
}

extern "C" void kernel_launch(void* const* d_in, const int* in_sizes, int n_in,
                              void* d_out, int out_size, void* d_ws, size_t ws_size,
                              hipStream_t stream) {
  (void)in_sizes; (void)n_in; (void)out_size; (void)ws_size;
  const float* xs = (const float*)d_in[0];
  const float* es = (const float*)d_in[1];
  const float* gs = (const float*)d_in[2];
  unsigned char* ws = (unsigned char*)d_ws;

  for (int comp = 0; comp < 3; ++comp) {
    const float* W1 = (const float*)d_in[3 + comp * 6 + 0];
    const float* W2 = (const float*)d_in[3 + comp * 6 + 2];
    const float* W3 = (const float*)d_in[3 + comp * 6 + 4];
    prep_weights<<<4, 256, 0, stream>>>(W1, W2, W3, ws + (size_t)comp * WS_COMP);
  }
  glstm<<<NBLOCKS, 512, 0, stream>>>(
      xs, es, gs, ws,
      (const float*)d_in[4],  (const float*)d_in[6],  (const float*)d_in[8],
      (const float*)d_in[10], (const float*)d_in[12], (const float*)d_in[14],
      (const float*)d_in[16], (const float*)d_in[18], (const float*)d_in[20],
      (float*)d_out);
}

// Round 14
// 284.648 us; speedup vs baseline: 1.5316x; 1.5316x over previous
//
#include <hip/hip_runtime.h>

typedef __attribute__((ext_vector_type(8))) short bf16x8;   // MFMA A/B frag
typedef __attribute__((ext_vector_type(4))) float f32x4;    // MFMA C/D frag
typedef __attribute__((ext_vector_type(4))) short s16x4;    // 4 bf16 (8 B)

__device__ __forceinline__ unsigned cvt_pk(float lo, float hi) {
  unsigned r;
  asm("v_cvt_pk_bf16_f32 %0, %1, %2" : "=v"(r) : "v"(lo), "v"(hi));
  return r;
}
__device__ __forceinline__ float bf2f(short s) {
  return __uint_as_float(((unsigned)(unsigned short)s) << 16);
}

#define LOG2E  1.4426950408889634f
#define LOG2E2 2.8853900817779268f

// ---------- geometry ----------
// ws per component: 4 matrices as A-operand fragments (W^T strips), bf16,
// PRESCALED: W1a,W1b by -log2e, W2 by +log2e, W3 by -log2e (exp2 consumes
// the MFMA accumulator directly; aA/aB/aC feed only sigmoids).
#define WS_MAT 32768
#define WS_COMP 131072
// 16 rows per block (all M divisible by 16 -> no validity predicates)
#define NODE_BLOCKS 3125
#define EDGE_BLOCKS 6250
#define GLOB_BLOCKS 32
#define NBLOCKS (NODE_BLOCKS + EDGE_BLOCKS + GLOB_BLOCKS)   // 9407

// swizzled byte offset within a [16 rows][256 B] LDS tile
#define SWZ(row, byte) ((row) * 256 + ((byte) ^ (((row) & 7) << 4)))
#define XBUF_B 4096
#define OBUF_B 4096
#define BIAS_OFF 20480            // 3*4096 + 2*4096
#define SMEM_B 22016              // + 1.5 KB biases

__global__ __launch_bounds__(256) void prep_weights(
    const float* __restrict__ W1, const float* __restrict__ W2,
    const float* __restrict__ W3, unsigned char* __restrict__ wsc) {
  const int m = blockIdx.x;   // 0=W1a 1=W1b 2=W2 3=W3
  const float* src; int rowoff = 0; float sc;
  if (m == 0)      { src = W1; sc = -LOG2E; }
  else if (m == 1) { src = W1; rowoff = 128; sc = -LOG2E; }
  else if (m == 2) { src = W2; sc =  LOG2E; }
  else             { src = W3; sc = -LOG2E; }
  short* dst = (short*)(wsc + (size_t)m * WS_MAT);
  for (int fi = threadIdx.x; fi < 2048; fi += 256) {
    int w = fi >> 8, kc = (fi >> 6) & 3, lane = fi & 63;
    int cc = lane & 15, gg = lane >> 4;
    int wcol = 16 * w + cc;
    int kb = 32 * kc + 8 * gg + rowoff;
    union { bf16x8 h; unsigned u[4]; } v;
#pragma unroll
    for (int j = 0; j < 4; ++j)
      v.u[j] = cvt_pk(sc * src[(size_t)(kb + 2 * j) * 128 + wcol],
                      sc * src[(size_t)(kb + 2 * j + 1) * 128 + wcol]);
    *(bf16x8*)(dst + (size_t)fi * 8) = v.h;
  }
}

// x-only precompute (u, g3, aAx for the NEXT step). All trans here is slack
// (issue-bound region) -> pairwise-shared rcps to cut issue slots.
__device__ __forceinline__ void pre_tile(
    const char* xb, const float* blds, int row, int g, int w,
    const bf16x8* w1b, const bf16x8* w2, const bf16x8* w3,
    f32x4& u, f32x4& g3, f32x4& aAx) {
  bf16x8 xf[4];
#pragma unroll
  for (int kc = 0; kc < 4; ++kc)
    xf[kc] = *(const bf16x8*)(xb + SWZ(row, 64 * kc + 16 * g));
  s16x4 xe4 = *(const s16x4*)(xb + SWZ(row, 32 * w + 8 * g));
  const int bo = 16 * w + 4 * g;
  f32x4 aX = *(const f32x4*)(blds + bo);
  f32x4 aB = *(const f32x4*)(blds + 128 + bo);
  f32x4 aC = *(const f32x4*)(blds + 256 + bo);
#pragma unroll
  for (int kc = 0; kc < 4; ++kc) {
    aX = __builtin_amdgcn_mfma_f32_16x16x32_bf16(w1b[kc], xf[kc], aX, 0, 0, 0);
    aB = __builtin_amdgcn_mfma_f32_16x16x32_bf16(w2[kc],  xf[kc], aB, 0, 0, 0);
    aC = __builtin_amdgcn_mfma_f32_16x16x32_bf16(w3[kc],  xf[kc], aC, 0, 0, 0);
  }
#pragma unroll
  for (int p = 0; p < 2; ++p) {
    const int r0 = 2 * p, r1 = 2 * p + 1;
    float A0 = __builtin_amdgcn_exp2f(aB[r0]);                 // e^{aB}
    float A1 = __builtin_amdgcn_exp2f(aB[r1]);
    float E0 = __builtin_amdgcn_exp2f(LOG2E2 * bf2f(xe4[r0])); // e^{2xe}
    float E1 = __builtin_amdgcn_exp2f(LOG2E2 * bf2f(xe4[r1]));
    float du0 = (1.f + A0) * (E0 + 1.f);
    float du1 = (1.f + A1) * (E1 + 1.f);
    float ru = __builtin_amdgcn_rcpf(du0 * du1);
    u[r0] = (A0 * (E0 - 1.f)) * (ru * du1);
    u[r1] = (A1 * (E1 - 1.f)) * (ru * du0);
    float C0 = __builtin_amdgcn_exp2f(aC[r0]);                 // e^{-aC}
    float C1 = __builtin_amdgcn_exp2f(aC[r1]);
    float dg0 = 1.f + C0, dg1 = 1.f + C1;
    float rg = __builtin_amdgcn_rcpf(dg0 * dg1);
    g3[r0] = rg * dg1;
    g3[r1] = rg * dg0;
  }
  aAx = aX;
}

// serial (recurrent) part — LATENCY-shaped: prescaled exp2 direct from the
// MFMA accumulator, INDEPENDENT rcps (no pairing chains on the critical path).
__device__ __forceinline__ void ser_tile(
    const char* ofsrc, char* obw, bool wr, int row, int g, int w,
    const bf16x8* w1a, f32x4 aAx, f32x4 u, f32x4 g3, f32x4& st) {
  bf16x8 of[4];
#pragma unroll
  for (int kc = 0; kc < 4; ++kc)
    of[kc] = *(const bf16x8*)(ofsrc + SWZ(row, 64 * kc + 16 * g));
  f32x4 aA = aAx;   // = -log2e*(x@W1b + b1) (precomputed)
#pragma unroll
  for (int kc = 0; kc < 4; ++kc)
    aA = __builtin_amdgcn_mfma_f32_16x16x32_bf16(w1a[kc], of[kc], aA, 0, 0, 0);
  f32x4 ov;
#pragma unroll
  for (int ri = 0; ri < 4; ++ri) {
    float fgt = __builtin_amdgcn_rcpf(1.f + __builtin_amdgcn_exp2f(aA[ri]));
    st[ri] = st[ri] * fgt + u[ri];
    float T = __builtin_amdgcn_rcpf(1.f + __builtin_amdgcn_exp2f(LOG2E2 * st[ri]));
    ov[ri] = (1.f - 2.f * T) * g3[ri];
  }
  if (wr) {
    union { s16x4 v; unsigned uu[2]; } ob;
    ob.uu[0] = cvt_pk(ov[0], ov[1]);
    ob.uu[1] = cvt_pk(ov[2], ov[3]);
    *(s16x4*)(obw + SWZ(row, 32 * w + 8 * g)) = ob.v;
  }
}

__global__ __launch_bounds__(512, 4) void glstm(
    const float* __restrict__ xs, const float* __restrict__ es,
    const float* __restrict__ gs, const unsigned char* __restrict__ ws,
    const float* __restrict__ b1n, const float* __restrict__ b2n, const float* __restrict__ b3n,
    const float* __restrict__ b1e, const float* __restrict__ b2e, const float* __restrict__ b3e,
    const float* __restrict__ b1g, const float* __restrict__ b2g, const float* __restrict__ b3g,
    float* __restrict__ dout) {
  // LDS: 3 x-buffers (12 KB) + 2 out-buffers (8 KB) + biases (1.5 KB) = 21.5 KB
  __shared__ __align__(16) unsigned char smem[SMEM_B];

  const int bid = blockIdx.x, tid = threadIdx.x;
  const float* X; const float *B1, *B2, *B3; float *S, *O; int M, unit, comp;
  if (bid < NODE_BLOCKS) {
    X = xs; M = 50000;  S = dout;              O = dout + 19265536L;
    unit = bid; comp = 0; B1 = b1n; B2 = b2n; B3 = b3n;
  } else if (bid < NODE_BLOCKS + EDGE_BLOCKS) {
    X = es; M = 100000; S = dout + 6400000L;   O = dout + 25665536L;
    unit = bid - NODE_BLOCKS; comp = 1; B1 = b1e; B2 = b2e; B3 = b3e;
  } else {
    X = gs; M = 512;    S = dout + 19200000L;  O = dout + 38465536L;
    unit = bid - (NODE_BLOCKS + EDGE_BLOCKS); comp = 2; B1 = b1g; B2 = b2g; B3 = b3g;
  }

  const int w = tid >> 6, l = tid & 63, c = l & 15, g = l >> 4;
  const int Ra = unit * 16;

  // weights -> registers (once; reused across all rows and steps)
  bf16x8 wA[4][4];
  {
    const short* wsrc = (const short*)(ws + (size_t)comp * WS_COMP);
#pragma unroll
    for (int m = 0; m < 4; ++m)
#pragma unroll
      for (int kc = 0; kc < 4; ++kc)
        wA[m][kc] = *(const bf16x8*)(wsrc + (size_t)m * 16384 + ((w * 4 + kc) * 64 + l) * 8);
  }

  char* xb0 = (char*)smem;
  char* xb1 = (char*)smem + XBUF_B;
  char* xb2 = (char*)smem + 2 * XBUF_B;
  char* ob0 = (char*)smem + 3 * XBUF_B;
  char* ob1 = (char*)smem + 3 * XBUF_B + OBUF_B;
  float* blds = (float*)(smem + BIAS_OFF);

  // biases -> LDS, prescaled to match the weight prescale
  if (tid < 128) {
    blds[tid]       = -LOG2E * B1[tid];
    blds[128 + tid] =  LOG2E * B2[tid];
    blds[256 + tid] = -LOG2E * B3[tid];
  }

  const int srow = tid >> 5;              // 0..15
  const int sbyte = (tid & 31) * 8;       // bf16 byte col (8 B per thread)
  const int scol = (tid & 31) * 4;        // f32 col

  // ---- prologue: stage x(0)->xb0, x(1)->xb1 (4 f32 per thread per buffer)
  {
    const float* p0 = X + (size_t)(Ra + srow) * 128 + scol;
    const float* p1 = p0 + (size_t)M * 128;
    f32x4 a0 = *(const f32x4*)p0;
    f32x4 a1 = *(const f32x4*)p1;
    union { s16x4 v; unsigned u[2]; } o;
    o.u[0] = cvt_pk(a0[0], a0[1]); o.u[1] = cvt_pk(a0[2], a0[3]);
    *(s16x4*)(xb0 + SWZ(srow, sbyte)) = o.v;
    o.u[0] = cvt_pk(a1[0], a1[1]); o.u[1] = cvt_pk(a1[2], a1[3]);
    *(s16x4*)(xb1 + SWZ(srow, sbyte)) = o.v;
  }
  __syncthreads();

  // state init = x[0] (bf16-rounded); precompute step-0 x-terms from xb0
  f32x4 st, uu, g3, ax;
  {
    s16x4 e = *(const s16x4*)(xb0 + SWZ(c, 32 * w + 8 * g));
#pragma unroll
    for (int ri = 0; ri < 4; ++ri) st[ri] = bf2f(e[ri]);
  }
  pre_tile(xb0, blds, c, g, w, wA[1], wA[2], wA[3], uu, g3, ax);

  // rotating x buffers: xr = x(t+1), xw = target for x(t+2), xsp = x(t)
  char* xr = xb1; char* xw = xb2; char* xsp = xb0;
  char* orf = ob0; char* owf = ob1;

#pragma unroll 1
  for (int t = 0; t < 8; ++t) {
    // prefetch x(t+2): issue load early, LDS-write at step end
    f32x4 pa;
    const bool pf = (t < 6);
    if (pf) {
      const float* p = X + ((size_t)(t + 2) * M + Ra + srow) * 128 + scol;
      pa = *(const f32x4*)p;
    }

    // serial recurrent part (of = out(t-1); at t=0 out(-1)=x(0) in xsp)
    const char* ofs = (t == 0) ? (const char*)xsp : (const char*)orf;
    ser_tile(ofs, owf, t < 7, c, g, w, wA[0], ax, uu, g3, st);

    // precompute x-terms for step t+1 (independent of the serial chain)
    if (t < 7)
      pre_tile(xr, blds, c, g, w, wA[1], wA[2], wA[3], uu, g3, ax);

    // write staged x(t+2)
    if (pf) {
      union { s16x4 v; unsigned u[2]; } o;
      o.u[0] = cvt_pk(pa[0], pa[1]); o.u[1] = cvt_pk(pa[2], pa[3]);
      *(s16x4*)(xw + SWZ(srow, sbyte)) = o.v;
    }
    if (t < 7) __syncthreads();

    // rotate buffers
    char* tx = xsp; xsp = xr; xr = xw; xw = tx;
    char* to = orf; orf = owf; owf = to;
  }

  // ---- epilogue: out = tanh(st)*g3 (g3 holds step-7 values), store f32
  {
    float E0 = __builtin_amdgcn_exp2f(LOG2E2 * st[0]);
    float E1 = __builtin_amdgcn_exp2f(LOG2E2 * st[1]);
    float E2 = __builtin_amdgcn_exp2f(LOG2E2 * st[2]);
    float E3 = __builtin_amdgcn_exp2f(LOG2E2 * st[3]);
    float t0 = 1.f + E0, t1 = 1.f + E1, t2 = 1.f + E2, t3 = 1.f + E3;
    float rt01 = __builtin_amdgcn_rcpf(t0 * t1);
    float rt23 = __builtin_amdgcn_rcpf(t2 * t3);
    f32x4 ov;
    ov[0] = (1.f - 2.f * (rt01 * t1)) * g3[0];
    ov[1] = (1.f - 2.f * (rt01 * t0)) * g3[1];
    ov[2] = (1.f - 2.f * (rt23 * t3)) * g3[2];
    ov[3] = (1.f - 2.f * (rt23 * t2)) * g3[3];
    size_t o = (size_t)(Ra + c) * 128 + 16 * w + 4 * g;
    *(f32x4*)(S + o) = st;
    *(f32x4*)(O + o) = ov;
  }
}

extern "C" void kernel_launch(void* const* d_in, const int* in_sizes, int n_in,
                              void* d_out, int out_size, void* d_ws, size_t ws_size,
                              hipStream_t stream) {
  (void)in_sizes; (void)n_in; (void)out_size; (void)ws_size;
  const float* xs = (const float*)d_in[0];
  const float* es = (const float*)d_in[1];
  const float* gs = (const float*)d_in[2];
  unsigned char* ws = (unsigned char*)d_ws;

  for (int comp = 0; comp < 3; ++comp) {
    const float* W1 = (const float*)d_in[3 + comp * 6 + 0];
    const float* W2 = (const float*)d_in[3 + comp * 6 + 2];
    const float* W3 = (const float*)d_in[3 + comp * 6 + 4];
    prep_weights<<<4, 256, 0, stream>>>(W1, W2, W3, ws + (size_t)comp * WS_COMP);
  }
  glstm<<<NBLOCKS, 512, 0, stream>>>(
      xs, es, gs, ws,
      (const float*)d_in[4],  (const float*)d_in[6],  (const float*)d_in[8],
      (const float*)d_in[10], (const float*)d_in[12], (const float*)d_in[14],
      (const float*)d_in[16], (const float*)d_in[18], (const float*)d_in[20],
      (float*)d_out);
}